// Round 7
// baseline (176.885 us; speedup 1.0000x reference)
//
#include <hip/hip_runtime.h>

#define DEVI __device__ __forceinline__

typedef __attribute__((ext_vector_type(8))) short short8;
typedef __attribute__((ext_vector_type(4))) float f32x4;

struct alignas(8) us4 { unsigned short a, b, c, d; };

DEVI unsigned short f2bf(float f) {
    unsigned int u = __float_as_uint(f);
    u += 0x7fffU + ((u >> 16) & 1U);   // round-to-nearest-even
    return (unsigned short)(u >> 16);
}

DEVI f32x4 mfma16(short8 a, short8 b, f32x4 c) {
    return __builtin_amdgcn_mfma_f32_16x16x32_bf16(a, b, c, 0, 0, 0);
}

// pack two fp32 -> one u32 of two bf16 (round-half-up) in 3 VALU ops.
DEVI unsigned pk2(float lo, float hi) {
    unsigned r0 = __float_as_uint(lo) + 0x8000u;
    unsigned r1 = __float_as_uint(hi) + 0x8000u;
    return __builtin_amdgcn_perm(r1, r0, 0x07060302u);
}

DEVI short8 mk8(unsigned a, unsigned b, unsigned c, unsigned d) {
    union { unsigned u[4]; short8 s; } x;
    x.u[0] = a; x.u[1] = b; x.u[2] = c; x.u[3] = d;
    return x.s;
}

// global_load_lds: 16B/lane, LDS dest = wave-uniform base + lane*16 (linear).
#define GLDS(gp, sp) __builtin_amdgcn_global_load_lds( \
    (const __attribute__((address_space(1))) void*)(gp), \
    (__attribute__((address_space(3))) void*)(sp), 16, 0, 0)

#define VMCNT(n) asm volatile("s_waitcnt vmcnt(" #n ")" ::: "memory")
#define LGKMCNT0 asm volatile("s_waitcnt lgkmcnt(0)" ::: "memory")
#define MEMFENCE asm volatile("" ::: "memory")

// sqrt(log2(e)/8): pre-scale for QK/CQK so attn does exp2(sim) directly.
#define SQC 0.42466089f

// ---------------------------------------------------------------------------
// prep: 6 weight transposes, fp32 -> bf16: wT[n][k] = (bf16) w[k][n].
// ---------------------------------------------------------------------------
__global__ __launch_bounds__(256) void prep_kernel(
    const float* w0, const float* w1, const float* w2, const float* w3,
    const float* w4, const float* w5, short* __restrict__ wT)
{
    const float* srcs[6] = {w0, w1, w2, w3, w4, w5};
    int wz = blockIdx.x >> 6, rem = blockIdx.x & 63;
    const float* src = srcs[wz];
    short* dst = wT + (size_t)wz * 262144;
    int k0 = (rem >> 3) * 64, n0 = (rem & 7) * 64;
    __shared__ float tile[64][65];
    int t = threadIdx.x;
    int r = t >> 2, c0 = (t & 3) * 16;
#pragma unroll
    for (int ii = 0; ii < 4; ++ii) {
        float4 v = *(const float4*)(src + (size_t)(k0 + r) * 512 + n0 + c0 + ii * 4);
        tile[r][c0 + ii * 4 + 0] = v.x;
        tile[r][c0 + ii * 4 + 1] = v.y;
        tile[r][c0 + ii * 4 + 2] = v.z;
        tile[r][c0 + ii * 4 + 3] = v.w;
    }
    __syncthreads();
#pragma unroll
    for (int ii = 0; ii < 4; ++ii) {
        us4 o;
        o.a = f2bf(tile[c0 + ii * 4 + 0][r]);
        o.b = f2bf(tile[c0 + ii * 4 + 1][r]);
        o.c = f2bf(tile[c0 + ii * 4 + 2][r]);
        o.d = f2bf(tile[c0 + ii * 4 + 3][r]);
        *(us4*)(dst + (size_t)(n0 + r) * 512 + k0 + c0 + ii * 4) = o;
    }
}

// ---------------------------------------------------------------------------
// Input projections. A read as fp32 and converted in-register (pk2); W
// triple-buffered in LDS, single barrier per chunk. Outputs as before.
// ---------------------------------------------------------------------------
__global__ __launch_bounds__(256, 4) void proj_kernel(
    const float* __restrict__ x, const float* __restrict__ ctx,
    const short* __restrict__ wT,
    short* __restrict__ QK, short* __restrict__ CQK,
    short* __restrict__ VT, short* __restrict__ CVT)
{
    __shared__ __align__(16) char smem[24576];
    short (*wst)[4096] = (short (*)[4096])smem;   // [3][64 rows][8 slots]
    float (*ctile)[69] = (float (*)[69])smem;     // overlaid epilogue buffer

    int p = blockIdx.z;
    const float* src = (p & 1) ? ctx : x;
    const short* wm = wT + (size_t)p * 262144;
    int wid = threadIdx.x >> 6, lane = threadIdx.x & 63, il = lane & 15, q = lane >> 4;
    int mb = blockIdx.x * 64, nb = blockIdx.y * 64;
    int srow = lane >> 3, scol8 = ((lane & 7) ^ srow) << 3;
    int key = il & 7;
    const short* wL0 = wm + (size_t)(nb + wid * 16 + srow) * 512 + scol8;
    const short* wL1 = wL0 + 8 * 512;
#define PSTAGE(s, ck) do { \
    GLDS(wL0 + (ck) * 64, &wst[s][wid * 1024]); \
    GLDS(wL1 + (ck) * 64, &wst[s][wid * 1024 + 512]); } while (0)

    PSTAGE(0, 0);
    PSTAGE(1, 1);

    const float* arow = src + (size_t)(mb + wid * 16 + il) * 512;
    short8 a[16];
#pragma unroll
    for (int j = 0; j < 16; ++j) {
        float4 f0 = *(const float4*)(arow + j * 32 + q * 8);
        float4 f1 = *(const float4*)(arow + j * 32 + q * 8 + 4);
        a[j] = mk8(pk2(f0.x, f0.y), pk2(f0.z, f0.w),
                   pk2(f1.x, f1.y), pk2(f1.z, f1.w));
    }

    f32x4 acc[4] = {};
    int sA = 0, sB = 1, sC = 2;
    for (int ck = 0; ck < 8; ++ck) {
        if (ck < 7) { VMCNT(2); } else { VMCNT(0); }
        MEMFENCE;
        __builtin_amdgcn_s_barrier();
        if (ck < 6) PSTAGE(sC, ck + 2);
#pragma unroll
        for (int kk = 0; kk < 2; ++kk) {
#pragma unroll
            for (int nj = 0; nj < 4; ++nj) {
                short8 b = *(const short8*)(&wst[sA][(nj * 16 + il) * 64 + ((((kk << 2) + q) ^ key) << 3)]);
                acc[nj] = mfma16(a[ck * 2 + kk], b, acc[nj]);
            }
        }
        int t_ = sA; sA = sB; sB = sC; sC = t_;
    }
#undef PSTAGE

    __syncthreads();   // all waves done reading wst before ctile overlay
#pragma unroll
    for (int nj = 0; nj < 4; ++nj)
#pragma unroll
        for (int r = 0; r < 4; ++r)
            ctile[wid * 16 + q * 4 + r][nj * 16 + il] = acc[nj][r];
    __syncthreads();
    int t = threadIdx.x, row = t >> 2, seg = (t & 3) << 4;
    short tmp[16];
    int h = blockIdx.y;
    if (p < 2) {
        short* dst = p ? CQK : QK;
        int i = mb + row, b2 = i >> 11, iL = i & 2047;
#pragma unroll
        for (int e = 0; e < 16; ++e) tmp[e] = (short)f2bf(ctile[row][seg + e] * SQC);
        short* dp = dst + (((size_t)b2 * 8 + h) * 2048 + iL) * 64 + seg;
        *(short8*)dp = *(const short8*)tmp;
        *(short8*)(dp + 8) = *(const short8*)(tmp + 8);
    } else {
        short* dst = (p == 2) ? VT : CVT;
        int d = row;
        int i0 = mb + seg, b2 = i0 >> 11, iL = i0 & 2047;
#pragma unroll
        for (int e = 0; e < 16; ++e) tmp[e] = (short)f2bf(ctile[seg + e][d]);
        short* dp = dst + (((size_t)b2 * 8 + h) * 64 + d) * 2048 + iL;
        *(short8*)dp = *(const short8*)tmp;
        *(short8*)(dp + 8) = *(const short8*)(tmp + 8);
    }
}

// ---------------------------------------------------------------------------
// Fused attention, both directions. 4 waves x 32 rows = 128 rows/block.
// Triple-buffered Bt/Wt, ONE barrier per tile (stage-after-barrier into the
// slot everyone just vacated). A-tile aliases slot 2 (dead after prologue).
// Swapped sim + rho-permuted Bt rows => in-lane P pack via pk2.
// ---------------------------------------------------------------------------
__global__ __launch_bounds__(256, 3) void attn_kernel(
    const short* __restrict__ QK, const short* __restrict__ CQK,
    const short* __restrict__ VT, const short* __restrict__ CVT,
    short* __restrict__ OUTx, short* __restrict__ OUTc)
{
    __shared__ __align__(16) short Bt[3][4096];  // 3 x 8KB, rho-permuted rows
    __shared__ __align__(16) short Wt[3][4096];  // 3 x 8KB

    int flat = blockIdx.x + (blockIdx.y << 4) + (blockIdx.z << 8);
    int bh = flat & 15;
    int ib = (flat >> 4) & 15;
    int z = flat >> 8;

    const short* Arows = z ? CQK : QK;
    const short* Bcols = z ? QK : CQK;
    const short* WTm   = z ? VT : CVT;
    short* Om          = z ? OUTc : OUTx;

    int b_ = bh >> 3, h = bh & 7;
    int w = threadIdx.x >> 6, lane = threadIdx.x & 63, il = lane & 15, q = lane >> 4;
    const short* Ab = Arows + (size_t)bh * 131072;
    const short* Bb = Bcols + (size_t)bh * 131072;
    const short* Wb = WTm + (size_t)bh * 131072;

    int srow = lane >> 3;
    int scol8 = ((lane & 7) ^ srow) << 3;
    int key = il & 7;

    // Bt row permutation: position p holds source row j(p) with
    // j5=p5, j4=p3, j3=p2, j2=p4, j1=p1, j0=p0.
    int p0 = w * 16 + srow, p1 = p0 + 8;
    int j0p = (p0 & 0x23) | ((p0 & 0x0C) << 1) | ((p0 & 0x10) >> 2);
    int j1p = (p1 & 0x23) | ((p1 & 0x0C) << 1) | ((p1 & 0x10) >> 2);
    const short* BbL0 = Bb + j0p * 64 + scol8;
    const short* BbL1 = Bb + j1p * 64 + scol8;
    const short* WbL0 = Wb + (size_t)p0 * 2048 + scol8;
    const short* WbL1 = WbL0 + 8 * 2048;

#define STAGE(s, jt) do { \
    GLDS(BbL0 + (jt) * 4096, &Bt[s][w * 1024]); \
    GLDS(BbL1 + (jt) * 4096, &Bt[s][w * 1024 + 512]); \
    GLDS(WbL0 + (jt) * 64, &Wt[s][w * 1024]); \
    GLDS(WbL1 + (jt) * 64, &Wt[s][w * 1024 + 512]); } while (0)

    // prologue: own 32 A-rows into slot-2 region (dead after aq read), then
    // tiles 0 and 1 into slots 0 and 1.
    short* Areg = (w < 2) ? &Bt[2][0] : &Wt[2][0];
    int ar = (w & 1) * 2048;
    {
        const short* AbL = Ab + (size_t)(ib * 128 + w * 32 + srow) * 64 + scol8;
        GLDS(AbL, Areg + ar);
        GLDS(AbL + 512, Areg + ar + 512);
        GLDS(AbL + 1024, Areg + ar + 1024);
        GLDS(AbL + 1536, Areg + ar + 1536);
    }
    STAGE(0, 0);
    STAGE(1, 1);
    VMCNT(8);  // own A rows complete (tiles 0/1 still in flight)

    short8 aq[2][2];
#pragma unroll
    for (int rg = 0; rg < 2; ++rg) {
        const short* base = Areg + ((w & 1) * 32 + rg * 16 + il) * 64;
        aq[rg][0] = *(const short8*)(base + ((q ^ key) << 3));
        aq[rg][1] = *(const short8*)(base + (((q + 4) ^ key) << 3));
    }
    LGKMCNT0;                              // aq reads serviced before slot-2 reuse
    __builtin_amdgcn_sched_barrier(0);

    f32x4 acc[2][4] = {};
    float s_acc[2] = {0.f, 0.f};

    int sA = 0, sB = 1, sC = 2;
    for (int jt = 0; jt < 32; ++jt) {
        if (jt < 31) { VMCNT(4); } else { VMCNT(0); }
        MEMFENCE;
        __builtin_amdgcn_s_barrier();
        if (jt < 30) STAGE(sC, jt + 2);

        short8 b0[4], b1[4];
#pragma unroll
        for (int nj = 0; nj < 4; ++nj) {
            const short* bb = &Bt[sA][(nj * 16 + il) * 64];
            b0[nj] = *(const short8*)(bb + ((q ^ key) << 3));
            b1[nj] = *(const short8*)(bb + (((q + 4) ^ key) << 3));
        }

        unsigned pw[2][8];
#pragma unroll
        for (int rg = 0; rg < 2; ++rg) {
#pragma unroll
            for (int nj = 0; nj < 4; ++nj) {
                f32x4 zz = {};
                zz = mfma16(b0[nj], aq[rg][0], zz);
                zz = mfma16(b1[nj], aq[rg][1], zz);
                float e0 = __builtin_amdgcn_exp2f(zz[0]);
                float e1 = __builtin_amdgcn_exp2f(zz[1]);
                float e2 = __builtin_amdgcn_exp2f(zz[2]);
                float e3 = __builtin_amdgcn_exp2f(zz[3]);
                s_acc[rg] += (e0 + e1) + (e2 + e3);
                pw[rg][nj * 2 + 0] = pk2(e0, e1);
                pw[rg][nj * 2 + 1] = pk2(e2, e3);
            }
        }
        short8 pa0[2] = { mk8(pw[0][0], pw[0][1], pw[0][2], pw[0][3]),
                          mk8(pw[1][0], pw[1][1], pw[1][2], pw[1][3]) };
        short8 pa1[2] = { mk8(pw[0][4], pw[0][5], pw[0][6], pw[0][7]),
                          mk8(pw[1][4], pw[1][5], pw[1][6], pw[1][7]) };

#pragma unroll
        for (int nd = 0; nd < 4; ++nd) {
            const short* vv = &Wt[sA][(nd * 16 + il) * 64];
            short8 v0 = *(const short8*)(vv + ((q ^ key) << 3));
            short8 v1 = *(const short8*)(vv + (((q + 4) ^ key) << 3));
#pragma unroll
            for (int rg = 0; rg < 2; ++rg) {
                acc[rg][nd] = mfma16(pa0[rg], v0, acc[rg][nd]);
                acc[rg][nd] = mfma16(pa1[rg], v1, acc[rg][nd]);
            }
        }
        int t_ = sA; sA = sB; sB = sC; sC = t_;
    }
#undef STAGE

    // Row sums: reduce over q-lanes, redistribute to output-row layout.
    f32x4 inv[2];
#pragma unroll
    for (int rg = 0; rg < 2; ++rg) {
        float s = s_acc[rg];
        s += __shfl_xor(s, 16);
        s += __shfl_xor(s, 32);
#pragma unroll
        for (int r = 0; r < 4; ++r)
            inv[rg][r] = 1.0f / __shfl(s, q * 4 + r);
    }

#pragma unroll
    for (int rg = 0; rg < 2; ++rg) {
#pragma unroll
        for (int nd = 0; nd < 4; ++nd) {
#pragma unroll
            for (int r = 0; r < 4; ++r) {
                int i = ib * 128 + w * 32 + rg * 16 + q * 4 + r;
                Om[((size_t)b_ * 2048 + i) * 512 + h * 64 + nd * 16 + il] =
                    (short)f2bf(acc[rg][nd][r] * inv[rg][r]);
            }
        }
    }
}

// ---------------------------------------------------------------------------
// Output projections (+bias), fp32 out. A in registers, W triple-buffered,
// single barrier per chunk.
// ---------------------------------------------------------------------------
__global__ __launch_bounds__(256, 4) void final_kernel(
    const short* __restrict__ OUTx, const short* __restrict__ OUTc,
    const short* __restrict__ wT,
    const float* __restrict__ b_out, const float* __restrict__ b_cout,
    float* __restrict__ dout)
{
    __shared__ __align__(16) short wst[3][4096];
    int z = blockIdx.z;
    const short* Am = z ? OUTc : OUTx;
    const short* wm = wT + (size_t)(4 + z) * 262144;
    const float* bias = z ? b_cout : b_out;
    float* D = dout + (size_t)z * 2097152;
    int wid = threadIdx.x >> 6, lane = threadIdx.x & 63, il = lane & 15, q = lane >> 4;
    int mb = blockIdx.x * 64, nb = blockIdx.y * 64;
    int srow = lane >> 3, scol8 = ((lane & 7) ^ srow) << 3;
    int key = il & 7;
    const short* wL0 = wm + (size_t)(nb + wid * 16 + srow) * 512 + scol8;
    const short* wL1 = wL0 + 8 * 512;
#define FSTAGE(s, ck) do { \
    GLDS(wL0 + (ck) * 64, &wst[s][wid * 1024]); \
    GLDS(wL1 + (ck) * 64, &wst[s][wid * 1024 + 512]); } while (0)

    FSTAGE(0, 0);
    FSTAGE(1, 1);
    const short* arow = Am + (size_t)(mb + wid * 16 + il) * 512;
    short8 a[16];
#pragma unroll
    for (int j = 0; j < 16; ++j) a[j] = *(const short8*)(arow + j * 32 + (q << 3));

    f32x4 acc[4] = {};
    int sA = 0, sB = 1, sC = 2;
    for (int ck = 0; ck < 8; ++ck) {
        if (ck < 7) { VMCNT(2); } else { VMCNT(0); }
        MEMFENCE;
        __builtin_amdgcn_s_barrier();
        if (ck < 6) FSTAGE(sC, ck + 2);
#pragma unroll
        for (int kk = 0; kk < 2; ++kk) {
#pragma unroll
            for (int nj = 0; nj < 4; ++nj) {
                short8 b = *(const short8*)(&wst[sA][(nj * 16 + il) * 64 + ((((kk << 2) + q) ^ key) << 3)]);
                acc[nj] = mfma16(a[ck * 2 + kk], b, acc[nj]);
            }
        }
        int t_ = sA; sA = sB; sB = sC; sC = t_;
    }
#undef FSTAGE

#pragma unroll
    for (int nj = 0; nj < 4; ++nj) {
        int c = nb + nj * 16 + il;
        float bi = bias[c];
#pragma unroll
        for (int r = 0; r < 4; ++r) {
            int m = mb + wid * 16 + q * 4 + r;
            D[(size_t)m * 512 + c] = acc[nj][r] + bi;
        }
    }
}

// ---------------------------------------------------------------------------
extern "C" void kernel_launch(void* const* d_in, const int* in_sizes, int n_in,
                              void* d_out, int out_size, void* d_ws, size_t ws_size,
                              hipStream_t stream)
{
    (void)in_sizes; (void)n_in; (void)out_size; (void)ws_size;
    const float* x      = (const float*)d_in[0];
    const float* ctx    = (const float*)d_in[1];
    const float* w_qk   = (const float*)d_in[2];
    const float* w_cqk  = (const float*)d_in[3];
    const float* w_v    = (const float*)d_in[4];
    const float* w_cv   = (const float*)d_in[5];
    const float* w_out  = (const float*)d_in[6];
    const float* b_out  = (const float*)d_in[7];
    const float* w_cout = (const float*)d_in[8];
    const float* b_cout = (const float*)d_in[9];
    float* dout = (float*)d_out;

    char* ws = (char*)d_ws;
    const size_t WSZ = (size_t)512 * 512 * 2;       // one bf16 weight matrix
    const size_t TSZ = (size_t)16 * 2048 * 64 * 2;  // one head-split bf16 tensor (4 MB)
    short* wT   = (short*)ws;                        // 6 * WSZ = 3 MB
    short* OUTx = (short*)(ws + 6 * WSZ);
    short* OUTc = (short*)(ws + 6 * WSZ + 1 * TSZ);
    short* QK   = (short*)(ws + 6 * WSZ + 2 * TSZ);
    short* CQK  = (short*)(ws + 6 * WSZ + 3 * TSZ);
    short* VT   = (short*)(ws + 6 * WSZ + 4 * TSZ);
    short* CVT  = (short*)(ws + 6 * WSZ + 5 * TSZ);  // total ~27.3 MB

    prep_kernel<<<dim3(384), 256, 0, stream>>>(w_qk, w_cqk, w_v, w_cv, w_out, w_cout, wT);
    proj_kernel<<<dim3(64, 8, 4), 256, 0, stream>>>(x, ctx, wT, QK, CQK, VT, CVT);
    attn_kernel<<<dim3(16, 16, 2), 256, 0, stream>>>(QK, CQK, VT, CVT, OUTx, OUTc);
    final_kernel<<<dim3(64, 8, 2), 256, 0, stream>>>(OUTx, OUTc, wT, b_out, b_cout, dout);
}

// Round 8
// 150.663 us; speedup vs baseline: 1.1740x; 1.1740x over previous
//
#include <hip/hip_runtime.h>

#define DEVI __device__ __forceinline__

typedef __attribute__((ext_vector_type(8))) short short8;
typedef __attribute__((ext_vector_type(4))) float f32x4;

struct alignas(8) us4 { unsigned short a, b, c, d; };

DEVI unsigned short f2bf(float f) {
    unsigned int u = __float_as_uint(f);
    u += 0x7fffU + ((u >> 16) & 1U);   // round-to-nearest-even
    return (unsigned short)(u >> 16);
}

DEVI f32x4 mfma16(short8 a, short8 b, f32x4 c) {
    return __builtin_amdgcn_mfma_f32_16x16x32_bf16(a, b, c, 0, 0, 0);
}

// pack two fp32 -> one u32 of two bf16 (round-half-up) in 3 VALU ops.
DEVI unsigned pk2(float lo, float hi) {
    unsigned r0 = __float_as_uint(lo) + 0x8000u;
    unsigned r1 = __float_as_uint(hi) + 0x8000u;
    return __builtin_amdgcn_perm(r1, r0, 0x07060302u);
}

DEVI short8 mk8(unsigned a, unsigned b, unsigned c, unsigned d) {
    union { unsigned u[4]; short8 s; } x;
    x.u[0] = a; x.u[1] = b; x.u[2] = c; x.u[3] = d;
    return x.s;
}

// global_load_lds: 16B/lane, LDS dest = wave-uniform base + lane*16 (linear).
#define GLDS(gp, sp) __builtin_amdgcn_global_load_lds( \
    (const __attribute__((address_space(1))) void*)(gp), \
    (__attribute__((address_space(3))) void*)(sp), 16, 0, 0)

#define VMCNT(n) asm volatile("s_waitcnt vmcnt(" #n ")" ::: "memory")
#define LGKMCNT0 asm volatile("s_waitcnt lgkmcnt(0)" ::: "memory")
#define MEMFENCE asm volatile("" ::: "memory")

// sqrt(log2(e)/8): pre-scale for QK/CQK so attn does exp2(sim) directly.
#define SQC 0.42466089f

// ---------------------------------------------------------------------------
// prep: z=0/1: x/ctx fp32->bf16; z=2: 6 weight transposes (bf16).
// ---------------------------------------------------------------------------
__global__ __launch_bounds__(256) void prep_kernel(
    const float* __restrict__ x, const float* __restrict__ ctx,
    const float* w0, const float* w1, const float* w2, const float* w3,
    const float* w4, const float* w5,
    short* __restrict__ Xb, short* __restrict__ Cb, short* __restrict__ wT)
{
    int z = blockIdx.z;
    if (z < 2) {
        const float* s = z ? ctx : x;
        short* d = z ? Cb : Xb;
        size_t t = (size_t)blockIdx.x * 256 + threadIdx.x;
        float4 v = *(const float4*)(s + t * 4);
        us4 o = { f2bf(v.x), f2bf(v.y), f2bf(v.z), f2bf(v.w) };
        *(us4*)(d + t * 4) = o;
        return;
    }
    if (blockIdx.x >= 384) return;
    const float* srcs[6] = {w0, w1, w2, w3, w4, w5};
    int wz = blockIdx.x >> 6, rem = blockIdx.x & 63;
    const float* src = srcs[wz];
    short* dst = wT + (size_t)wz * 262144;
    int k0 = (rem >> 3) * 64, n0 = (rem & 7) * 64;
    __shared__ float tile[64][65];
    int t = threadIdx.x;
    int r = t >> 2, c0 = (t & 3) * 16;
#pragma unroll
    for (int ii = 0; ii < 4; ++ii) {
        float4 v = *(const float4*)(src + (size_t)(k0 + r) * 512 + n0 + c0 + ii * 4);
        tile[r][c0 + ii * 4 + 0] = v.x;
        tile[r][c0 + ii * 4 + 1] = v.y;
        tile[r][c0 + ii * 4 + 2] = v.z;
        tile[r][c0 + ii * 4 + 3] = v.w;
    }
    __syncthreads();
#pragma unroll
    for (int ii = 0; ii < 4; ++ii) {
        us4 o;
        o.a = f2bf(tile[c0 + ii * 4 + 0][r]);
        o.b = f2bf(tile[c0 + ii * 4 + 1][r]);
        o.c = f2bf(tile[c0 + ii * 4 + 2][r]);
        o.d = f2bf(tile[c0 + ii * 4 + 3][r]);
        *(us4*)(dst + (size_t)(n0 + r) * 512 + k0 + c0 + ii * 4) = o;
    }
}

// ---------------------------------------------------------------------------
// Input projections, 128x128 tile, 8 waves. A (bf16 Xb/Cb) and B (wT) both
// staged via global_load_lds (pre-swizzled src), double-buffered, vmcnt(4).
// Wave (wm,wn)=(w&3,w>>2) owns 32x64 via acc[2][4]. Epilogue: ctile overlay,
// two wn-passes, coalesced layout-specific stores (p<2: [bh][i][d];
// p>=2: [bh][d][i]).
// ---------------------------------------------------------------------------
__global__ __launch_bounds__(512, 2) void proj_kernel(
    const short* __restrict__ Xb, const short* __restrict__ Cb,
    const short* __restrict__ wT,
    short* __restrict__ QK, short* __restrict__ CQK,
    short* __restrict__ VT, short* __restrict__ CVT)
{
    __shared__ __align__(16) char smem[65536];   // [2][A 16KB | B 16KB]
    float (*ctile)[65] = (float (*)[65])smem;    // overlay, 33.3 KB

    int p = blockIdx.z;
    const short* src = (p & 1) ? Cb : Xb;
    const short* wm = wT + (size_t)p * 262144;
    int w = threadIdx.x >> 6, lane = threadIdx.x & 63, il = lane & 15, q = lane >> 4;
    int wm_ = w & 3, wn = w >> 2;
    int mb = blockIdx.x * 128, nb = blockIdx.y * 128;
    int srow = lane >> 3, scol8 = ((lane & 7) ^ srow) << 3;
    int key = il & 7;
    const short* aL0 = src + (size_t)(mb + w * 16 + srow) * 512 + scol8;
    const short* aL1 = aL0 + 8 * 512;
    const short* bL0 = wm + (size_t)(nb + w * 16 + srow) * 512 + scol8;
    const short* bL1 = bL0 + 8 * 512;
#define TILE_A(buf) ((short*)smem + (buf) * 16384)
#define TILE_B(buf) ((short*)smem + (buf) * 16384 + 8192)
#define PSTAGE(buf, ck) do { \
    GLDS(aL0 + (ck) * 64, TILE_A(buf) + w * 1024); \
    GLDS(aL1 + (ck) * 64, TILE_A(buf) + w * 1024 + 512); \
    GLDS(bL0 + (ck) * 64, TILE_B(buf) + w * 1024); \
    GLDS(bL1 + (ck) * 64, TILE_B(buf) + w * 1024 + 512); } while (0)

    PSTAGE(0, 0);
    f32x4 acc[2][4] = {};
#pragma unroll
    for (int ck = 0; ck < 8; ++ck) {
        int buf = ck & 1;
        if (ck < 7) { PSTAGE(buf ^ 1, ck + 1); VMCNT(4); } else { VMCNT(0); }
        __builtin_amdgcn_s_barrier();
#pragma unroll
        for (int kk = 0; kk < 2; ++kk) {
            int ko = (((kk << 2) + q) ^ key) << 3;
            short8 a0 = *(const short8*)(TILE_A(buf) + (wm_ * 32 + il) * 64 + ko);
            short8 a1 = *(const short8*)(TILE_A(buf) + (wm_ * 32 + 16 + il) * 64 + ko);
#pragma unroll
            for (int nj = 0; nj < 4; ++nj) {
                short8 b = *(const short8*)(TILE_B(buf) + (wn * 64 + nj * 16 + il) * 64 + ko);
                acc[0][nj] = mfma16(a0, b, acc[0][nj]);
                acc[1][nj] = mfma16(a1, b, acc[1][nj]);
            }
        }
        MEMFENCE;
        __builtin_amdgcn_s_barrier();
    }
#undef PSTAGE

    int h0 = blockIdx.y * 2;
#pragma unroll
    for (int pass = 0; pass < 2; ++pass) {
        __syncthreads();
        if (wn == pass) {
#pragma unroll
            for (int mi = 0; mi < 2; ++mi)
#pragma unroll
                for (int nj = 0; nj < 4; ++nj)
#pragma unroll
                    for (int r = 0; r < 4; ++r)
                        ctile[wm_ * 32 + mi * 16 + q * 4 + r][nj * 16 + il] = acc[mi][nj][r];
        }
        __syncthreads();
        int t = threadIdx.x;
        int h = h0 + pass;
        short tmp[16];
        if (p < 2) {
            short* dst = p ? CQK : QK;
            int row = t >> 2, seg = (t & 3) << 4;
            int i = mb + row, b2 = i >> 11, iL = i & 2047;
#pragma unroll
            for (int e = 0; e < 16; ++e) tmp[e] = (short)f2bf(ctile[row][seg + e] * SQC);
            short* dp = dst + (((size_t)b2 * 8 + h) * 2048 + iL) * 64 + seg;
            *(short8*)dp = *(const short8*)tmp;
            *(short8*)(dp + 8) = *(const short8*)(tmp + 8);
        } else {
            short* dst = (p == 2) ? VT : CVT;
            int d = t >> 3, iseg = (t & 7) << 4;
            int i0 = mb + iseg, b2 = i0 >> 11, iL = i0 & 2047;
#pragma unroll
            for (int e = 0; e < 16; ++e) tmp[e] = (short)f2bf(ctile[iseg + e][d]);
            short* dp = dst + (((size_t)b2 * 8 + h) * 64 + d) * 2048 + iL;
            *(short8*)dp = *(const short8*)tmp;
            *(short8*)(dp + 8) = *(const short8*)(tmp + 8);
        }
    }
}

// ---------------------------------------------------------------------------
// Fused attention, both directions (unchanged from r7: triple-buffered Bt/Wt,
// one barrier per tile, swapped sim + rho-permuted rows, in-lane pk2 pack).
// ---------------------------------------------------------------------------
__global__ __launch_bounds__(256, 3) void attn_kernel(
    const short* __restrict__ QK, const short* __restrict__ CQK,
    const short* __restrict__ VT, const short* __restrict__ CVT,
    short* __restrict__ OUTx, short* __restrict__ OUTc)
{
    __shared__ __align__(16) short Bt[3][4096];
    __shared__ __align__(16) short Wt[3][4096];

    int flat = blockIdx.x + (blockIdx.y << 4) + (blockIdx.z << 8);
    int bh = flat & 15;
    int ib = (flat >> 4) & 15;
    int z = flat >> 8;

    const short* Arows = z ? CQK : QK;
    const short* Bcols = z ? QK : CQK;
    const short* WTm   = z ? VT : CVT;
    short* Om          = z ? OUTc : OUTx;

    int b_ = bh >> 3, h = bh & 7;
    int w = threadIdx.x >> 6, lane = threadIdx.x & 63, il = lane & 15, q = lane >> 4;
    const short* Ab = Arows + (size_t)bh * 131072;
    const short* Bb = Bcols + (size_t)bh * 131072;
    const short* Wb = WTm + (size_t)bh * 131072;

    int srow = lane >> 3;
    int scol8 = ((lane & 7) ^ srow) << 3;
    int key = il & 7;

    int p0 = w * 16 + srow, p1 = p0 + 8;
    int j0p = (p0 & 0x23) | ((p0 & 0x0C) << 1) | ((p0 & 0x10) >> 2);
    int j1p = (p1 & 0x23) | ((p1 & 0x0C) << 1) | ((p1 & 0x10) >> 2);
    const short* BbL0 = Bb + j0p * 64 + scol8;
    const short* BbL1 = Bb + j1p * 64 + scol8;
    const short* WbL0 = Wb + (size_t)p0 * 2048 + scol8;
    const short* WbL1 = WbL0 + 8 * 2048;

#define STAGE(s, jt) do { \
    GLDS(BbL0 + (jt) * 4096, &Bt[s][w * 1024]); \
    GLDS(BbL1 + (jt) * 4096, &Bt[s][w * 1024 + 512]); \
    GLDS(WbL0 + (jt) * 64, &Wt[s][w * 1024]); \
    GLDS(WbL1 + (jt) * 64, &Wt[s][w * 1024 + 512]); } while (0)

    short* Areg = (w < 2) ? &Bt[2][0] : &Wt[2][0];
    int ar = (w & 1) * 2048;
    {
        const short* AbL = Ab + (size_t)(ib * 128 + w * 32 + srow) * 64 + scol8;
        GLDS(AbL, Areg + ar);
        GLDS(AbL + 512, Areg + ar + 512);
        GLDS(AbL + 1024, Areg + ar + 1024);
        GLDS(AbL + 1536, Areg + ar + 1536);
    }
    STAGE(0, 0);
    STAGE(1, 1);
    VMCNT(8);

    short8 aq[2][2];
#pragma unroll
    for (int rg = 0; rg < 2; ++rg) {
        const short* base = Areg + ((w & 1) * 32 + rg * 16 + il) * 64;
        aq[rg][0] = *(const short8*)(base + ((q ^ key) << 3));
        aq[rg][1] = *(const short8*)(base + (((q + 4) ^ key) << 3));
    }
    LGKMCNT0;
    __builtin_amdgcn_sched_barrier(0);

    f32x4 acc[2][4] = {};
    float s_acc[2] = {0.f, 0.f};

    int sA = 0, sB = 1, sC = 2;
    for (int jt = 0; jt < 32; ++jt) {
        if (jt < 31) { VMCNT(4); } else { VMCNT(0); }
        MEMFENCE;
        __builtin_amdgcn_s_barrier();
        if (jt < 30) STAGE(sC, jt + 2);

        short8 b0[4], b1[4];
#pragma unroll
        for (int nj = 0; nj < 4; ++nj) {
            const short* bb = &Bt[sA][(nj * 16 + il) * 64];
            b0[nj] = *(const short8*)(bb + ((q ^ key) << 3));
            b1[nj] = *(const short8*)(bb + (((q + 4) ^ key) << 3));
        }

        unsigned pw[2][8];
#pragma unroll
        for (int rg = 0; rg < 2; ++rg) {
#pragma unroll
            for (int nj = 0; nj < 4; ++nj) {
                f32x4 zz = {};
                zz = mfma16(b0[nj], aq[rg][0], zz);
                zz = mfma16(b1[nj], aq[rg][1], zz);
                float e0 = __builtin_amdgcn_exp2f(zz[0]);
                float e1 = __builtin_amdgcn_exp2f(zz[1]);
                float e2 = __builtin_amdgcn_exp2f(zz[2]);
                float e3 = __builtin_amdgcn_exp2f(zz[3]);
                s_acc[rg] += (e0 + e1) + (e2 + e3);
                pw[rg][nj * 2 + 0] = pk2(e0, e1);
                pw[rg][nj * 2 + 1] = pk2(e2, e3);
            }
        }
        short8 pa0[2] = { mk8(pw[0][0], pw[0][1], pw[0][2], pw[0][3]),
                          mk8(pw[1][0], pw[1][1], pw[1][2], pw[1][3]) };
        short8 pa1[2] = { mk8(pw[0][4], pw[0][5], pw[0][6], pw[0][7]),
                          mk8(pw[1][4], pw[1][5], pw[1][6], pw[1][7]) };

#pragma unroll
        for (int nd = 0; nd < 4; ++nd) {
            const short* vv = &Wt[sA][(nd * 16 + il) * 64];
            short8 v0 = *(const short8*)(vv + ((q ^ key) << 3));
            short8 v1 = *(const short8*)(vv + (((q + 4) ^ key) << 3));
#pragma unroll
            for (int rg = 0; rg < 2; ++rg) {
                acc[rg][nd] = mfma16(pa0[rg], v0, acc[rg][nd]);
                acc[rg][nd] = mfma16(pa1[rg], v1, acc[rg][nd]);
            }
        }
        int t_ = sA; sA = sB; sB = sC; sC = t_;
    }
#undef STAGE

    f32x4 inv[2];
#pragma unroll
    for (int rg = 0; rg < 2; ++rg) {
        float s = s_acc[rg];
        s += __shfl_xor(s, 16);
        s += __shfl_xor(s, 32);
#pragma unroll
        for (int r = 0; r < 4; ++r)
            inv[rg][r] = 1.0f / __shfl(s, q * 4 + r);
    }

#pragma unroll
    for (int rg = 0; rg < 2; ++rg) {
#pragma unroll
        for (int nd = 0; nd < 4; ++nd) {
#pragma unroll
            for (int r = 0; r < 4; ++r) {
                int i = ib * 128 + w * 32 + rg * 16 + q * 4 + r;
                Om[((size_t)b_ * 2048 + i) * 512 + h * 64 + nd * 16 + il] =
                    (short)f2bf(acc[rg][nd][r] * inv[rg][r]);
            }
        }
    }
}

// ---------------------------------------------------------------------------
// Output projections (+bias), fp32 out. 128x128 tile, 8 waves, A+B staged,
// direct coalesced fp32 epilogue.
// ---------------------------------------------------------------------------
__global__ __launch_bounds__(512, 2) void final_kernel(
    const short* __restrict__ OUTx, const short* __restrict__ OUTc,
    const short* __restrict__ wT,
    const float* __restrict__ b_out, const float* __restrict__ b_cout,
    float* __restrict__ dout)
{
    __shared__ __align__(16) char smem[65536];
    int z = blockIdx.z;
    const short* Am = z ? OUTc : OUTx;
    const short* wm = wT + (size_t)(4 + z) * 262144;
    const float* bias = z ? b_cout : b_out;
    float* D = dout + (size_t)z * 2097152;
    int w = threadIdx.x >> 6, lane = threadIdx.x & 63, il = lane & 15, q = lane >> 4;
    int wm_ = w & 3, wn = w >> 2;
    int mb = blockIdx.x * 128, nb = blockIdx.y * 128;
    int srow = lane >> 3, scol8 = ((lane & 7) ^ srow) << 3;
    int key = il & 7;
    const short* aL0 = Am + (size_t)(mb + w * 16 + srow) * 512 + scol8;
    const short* aL1 = aL0 + 8 * 512;
    const short* bL0 = wm + (size_t)(nb + w * 16 + srow) * 512 + scol8;
    const short* bL1 = bL0 + 8 * 512;
#define FSTAGE(buf, ck) do { \
    GLDS(aL0 + (ck) * 64, TILE_A(buf) + w * 1024); \
    GLDS(aL1 + (ck) * 64, TILE_A(buf) + w * 1024 + 512); \
    GLDS(bL0 + (ck) * 64, TILE_B(buf) + w * 1024); \
    GLDS(bL1 + (ck) * 64, TILE_B(buf) + w * 1024 + 512); } while (0)

    FSTAGE(0, 0);
    f32x4 acc[2][4] = {};
#pragma unroll
    for (int ck = 0; ck < 8; ++ck) {
        int buf = ck & 1;
        if (ck < 7) { FSTAGE(buf ^ 1, ck + 1); VMCNT(4); } else { VMCNT(0); }
        __builtin_amdgcn_s_barrier();
#pragma unroll
        for (int kk = 0; kk < 2; ++kk) {
            int ko = (((kk << 2) + q) ^ key) << 3;
            short8 a0 = *(const short8*)(TILE_A(buf) + (wm_ * 32 + il) * 64 + ko);
            short8 a1 = *(const short8*)(TILE_A(buf) + (wm_ * 32 + 16 + il) * 64 + ko);
#pragma unroll
            for (int nj = 0; nj < 4; ++nj) {
                short8 b = *(const short8*)(TILE_B(buf) + (wn * 64 + nj * 16 + il) * 64 + ko);
                acc[0][nj] = mfma16(a0, b, acc[0][nj]);
                acc[1][nj] = mfma16(a1, b, acc[1][nj]);
            }
        }
        MEMFENCE;
        __builtin_amdgcn_s_barrier();
    }
#undef FSTAGE

#pragma unroll
    for (int nj = 0; nj < 4; ++nj) {
        int c = nb + wn * 64 + nj * 16 + il;
        float bi = bias[c];
#pragma unroll
        for (int mi = 0; mi < 2; ++mi)
#pragma unroll
            for (int r = 0; r < 4; ++r) {
                int m = mb + wm_ * 32 + mi * 16 + q * 4 + r;
                D[(size_t)m * 512 + c] = acc[mi][nj][r] + bi;
            }
    }
}

// ---------------------------------------------------------------------------
extern "C" void kernel_launch(void* const* d_in, const int* in_sizes, int n_in,
                              void* d_out, int out_size, void* d_ws, size_t ws_size,
                              hipStream_t stream)
{
    (void)in_sizes; (void)n_in; (void)out_size; (void)ws_size;
    const float* x      = (const float*)d_in[0];
    const float* ctx    = (const float*)d_in[1];
    const float* w_qk   = (const float*)d_in[2];
    const float* w_cqk  = (const float*)d_in[3];
    const float* w_v    = (const float*)d_in[4];
    const float* w_cv   = (const float*)d_in[5];
    const float* w_out  = (const float*)d_in[6];
    const float* b_out  = (const float*)d_in[7];
    const float* w_cout = (const float*)d_in[8];
    const float* b_cout = (const float*)d_in[9];
    float* dout = (float*)d_out;

    char* ws = (char*)d_ws;
    const size_t WSZ = (size_t)512 * 512 * 2;       // one bf16 weight matrix
    const size_t TSZ = (size_t)16 * 2048 * 64 * 2;  // one head-split bf16 tensor (4 MB)
    short* wT   = (short*)ws;                        // 6 * WSZ = 3 MB
    short* Xb   = (short*)(ws + 6 * WSZ);            // aliased with OUTx (disjoint lifetime)
    short* Cb   = (short*)(ws + 6 * WSZ + 1 * TSZ);  // aliased with OUTc
    short* QK   = (short*)(ws + 6 * WSZ + 2 * TSZ);
    short* CQK  = (short*)(ws + 6 * WSZ + 3 * TSZ);
    short* VT   = (short*)(ws + 6 * WSZ + 4 * TSZ);
    short* CVT  = (short*)(ws + 6 * WSZ + 5 * TSZ);  // total ~27.3 MB
    short* OUTx = Xb;
    short* OUTc = Cb;

    prep_kernel<<<dim3(2048, 1, 3), 256, 0, stream>>>(
        x, ctx, w_qk, w_cqk, w_v, w_cv, w_out, w_cout, Xb, Cb, wT);
    proj_kernel<<<dim3(32, 4, 4), 512, 0, stream>>>(Xb, Cb, wT, QK, CQK, VT, CVT);
    attn_kernel<<<dim3(16, 16, 2), 256, 0, stream>>>(QK, CQK, VT, CVT, OUTx, OUTc);
    final_kernel<<<dim3(32, 4, 2), 512, 0, stream>>>(OUTx, OUTc, wT, b_out, b_cout, dout);
}